// Round 10
// baseline (99.830 us; speedup 1.0000x reference)
//
#include <hip/hip_runtime.h>
#include <hip/hip_bf16.h>

#define FRCP(x)  __builtin_amdgcn_rcpf(x)
#define FSQRT(x) __builtin_amdgcn_sqrtf(x)
#define FLOG2(x) __builtin_amdgcn_logf(x)    // v_log_f32: log2(x)
#define FEXP2(x) __builtin_amdgcn_exp2f(x)   // v_exp_f32: 2^x

#define GLOBAL_AS __attribute__((address_space(1)))
#define LDS_AS    __attribute__((address_space(3)))

// One thread = one particle. 256 particles/block.
// Memory path (round 10): HBM -> LDS via global_load_lds (async DMA, width 16,
// no VGPR round-trip; LDS layout MUST be contiguous in lane order — no
// padding), stride-9 LDS reads (odd stride -> 2 lanes/bank, conflict-free),
// compute in registers, DIRECT scalar global stores (9 dwords/thread; one
// wave's stores cover a contiguous 2304B region, L2 write-merges). No second
// barrier, no output LDS round-trip.
//
// STRUCTURE: no eigenvectors (round 8) + no eigen-iteration (round 9).
// Output = F * p(A) + wd*I, A = F^T F, p = quadratic Newton interpolation of
// the spectral weights w_i at the eigenvalues. Matrix-function form makes
// output error ~ (|p'|+|w'|)*dLambda — decoupled from eigenvector/gap
// conditioning — so closed-form trigonometric eigenvalues (Smith's method)
// with ~1e-6 accuracy suffice. cos(acos(r)/3) via cubic fit in
// u = sqrt((1+r)/2) + 1 guarded Newton on 4c^3-3c=r.
//
// LOCKED decisions (HW-tested):
//  - f32 output buffer (bf16 store failed round 1).
//  - fast rcp/sqrt + raw v_log_f32/v_exp_f32: absmax stays at bf16 floor.
//  - matrix-function recomposition (rounds 8-9 both at bf16 floor).
__global__ __launch_bounds__(256) void physics_svd_kernel(
    const float* __restrict__ gF,
    const float* __restrict__ p_Elog,
    const float* __restrict__ p_nu,
    const float* __restrict__ p_ys,
    const float* __restrict__ p_alpha,
    const float* __restrict__ p_coh,
    float* __restrict__ gOut,
    int B)
{
    __shared__ __align__(16) float lds[2304];   // 256 particles * 9 floats

    const int tid   = threadIdx.x;
    const int pbase = blockIdx.x * 256;
    const int nhere = min(256, B - pbase);
    const int nflt  = nhere * 9;

    // ---- phase 1: stage F into LDS ----
    if (nhere == 256) {
        const float4* g4 = reinterpret_cast<const float4*>(gF + (size_t)pbase * 9);
        float4* l4 = reinterpret_cast<float4*>(lds);
        // 576 float4 = 256 + 256 + 64; dest = wave-uniform base + lane*16
        __builtin_amdgcn_global_load_lds(
            (const GLOBAL_AS void*)(g4 + tid),
            (LDS_AS void*)(l4 + tid), 16, 0, 0);
        __builtin_amdgcn_global_load_lds(
            (const GLOBAL_AS void*)(g4 + tid + 256),
            (LDS_AS void*)(l4 + tid + 256), 16, 0, 0);
        if (tid < 64)
            __builtin_amdgcn_global_load_lds(
                (const GLOBAL_AS void*)(g4 + tid + 512),
                (LDS_AS void*)(l4 + tid + 512), 16, 0, 0);
    } else {
        for (int j = tid; j < nflt; j += 256) lds[j] = gF[(size_t)pbase * 9 + j];
    }

    // material scalars (uniform broadcast loads -> SGPRs); overlaps load latency
    const float E  = __expf(p_Elog[0]);
    const float nu = p_nu[0];
    const float ys = p_ys[0];
    const float al = p_alpha[0];
    const float co = p_coh[0];
    const float mu = E / (2.0f * (1.0f + nu));
    const float la = E * nu / ((1.0f + nu) * (1.0f - 2.0f * nu));
    const float ys_2mu = ys / (2.0f * mu);
    const float kk     = (3.0f * la + 2.0f * mu) / (2.0f * mu) * al;
    const float lco2   = co * 1.4426950f;   // log2(exp(co))

    const float LN2     = 0.69314718f;
    const float L2_001  = -6.6438562f;      // log2(0.01)  (plasticine sigma floor)
    const float L2_005  = -4.3219281f;      // log2(0.05)  (sand sigma floor)

    __syncthreads();   // compiler emits vmcnt drain for global_load_lds here

    if (tid < nhere) {
        float f[9];
        #pragma unroll
        for (int k = 0; k < 9; ++k) f[k] = lds[tid * 9 + k];

        // A = F^T F (symmetric)
        float b00 = f[0]*f[0] + f[3]*f[3] + f[6]*f[6];
        float b01 = f[0]*f[1] + f[3]*f[4] + f[6]*f[7];
        float b02 = f[0]*f[2] + f[3]*f[5] + f[6]*f[8];
        float b11 = f[1]*f[1] + f[4]*f[4] + f[7]*f[7];
        float b12 = f[1]*f[2] + f[4]*f[5] + f[7]*f[8];
        float b22 = f[2]*f[2] + f[5]*f[5] + f[8]*f[8];

        // ---- closed-form eigenvalues (Smith's trigonometric method) ----
        float m3  = (b00 + b11 + b22) * (1.0f/3.0f);
        float k00 = b00 - m3, k11 = b11 - m3, k22 = b22 - m3;
        float pp  = (k00*k00 + k11*k11 + k22*k22) * (1.0f/6.0f)
                  + (b01*b01 + b02*b02 + b12*b12) * (1.0f/3.0f);
        float qq  = 0.5f * (k00*(k11*k22 - b12*b12)
                          - b01*(b01*k22 - b12*b02)
                          + b02*(b01*b12 - k11*b02));
        float sp  = FSQRT(pp);
        float rr  = qq * FRCP(fmaxf(pp * sp, 1e-30f));
        rr = fminf(fmaxf(rr, -1.0f), 1.0f);
        // c = cos(acos(rr)/3): cubic init in u = sqrt((1+r)/2), 1 Newton on 4c^3-3c=r
        float uu = FSQRT(__builtin_fmaf(0.5f, rr, 0.5f));
        float cc = 0.5f + uu * (0.57735027f + uu * (-0.09914500f + uu * 0.02179470f));
        float c2v = cc * cc;
        float fv  = cc * __builtin_fmaf(4.0f, c2v, -3.0f) - rr;
        float fpv = __builtin_fmaf(12.0f, c2v, -3.0f);
        cc -= fv * FRCP(fmaxf(fpv, 1e-4f));
        cc = fminf(fmaxf(cc, 0.5f), 1.0f);
        float ssin = FSQRT(fmaxf(__builtin_fmaf(-cc, cc, 1.0f), 0.0f));
        float sp2 = sp + sp;
        float l0 = __builtin_fmaf(sp2, cc, m3);                         // largest
        float ca = __builtin_fmaf(-0.8660254f, ssin, -0.5f * cc);       // cos(phi+2pi/3)
        float l1 = __builtin_fmaf(sp2, ca, m3);                         // smallest
        float l2 = 3.0f * m3 - l0 - l1;                                 // middle (trace)
        l0 = fmaxf(l0, 1e-20f);
        l1 = fmaxf(l1, 1e-20f);
        l2 = fmaxf(l2, 1e-20f);

        float li0 = FLOG2(l0), li1 = FLOG2(l1), li2 = FLOG2(l2);
        float hl0 = 0.5f * li0, hl1 = 0.5f * li1, hl2 = 0.5f * li2;

        // ---- plasticine (von Mises) in log2 domain ----
        float p0 = fmaxf(hl0, L2_001);
        float p1 = fmaxf(hl1, L2_001);
        float p2 = fmaxf(hl2, L2_001);
        float mp = (p0 + p1 + p2) * (1.0f/3.0f);
        float bb0 = p0 - mp, bb1 = p1 - mp, bb2 = p2 - mp;
        float bn = LN2 * FSQRT(bb0*bb0 + bb1*bb1 + bb2*bb2) + 1e-5f;  // natural norm
        float rp = fmaxf(bn - ys_2mu, 0.0f) * FRCP(bn);

        // ---- sand (Drucker-Prager) in log2 domain ----
        float q0 = fmaxf(hl0, L2_005);
        float q1 = fmaxf(hl1, L2_005);
        float q2 = fmaxf(hl2, L2_005);
        float mq = (q0 + q1 + q2) * (1.0f/3.0f);
        float hb0 = q0 - mq, hb1 = q1 - mq, hb2 = q2 - mq;
        float hn = LN2 * FSQRT(hb0*hb0 + hb1*hb1 + hb2*hb2);          // natural norm
        float st = LN2 * (q0 + q1 + q2) - 3.0f * co;                  // natural trace
        bool cond = st < 0.0f;
        float rs = fmaxf(hn + kk * st, 0.0f) * FRCP(fmaxf(hn, 1e-20f));

        // ---- spectral weights w_i = (0.5*gp_i + 0.3*gs_i)/sigma_i ----
        float w0 = 0.5f * FEXP2(p0 - rp*bb0 - hl0)
                 + 0.3f * FEXP2(cond ? (q0 - rs*hb0 - hl0) : (lco2 - hl0));
        float w1 = 0.5f * FEXP2(p1 - rp*bb1 - hl1)
                 + 0.3f * FEXP2(cond ? (q1 - rs*hb1 - hl1) : (lco2 - hl1));
        float w2 = 0.5f * FEXP2(p2 - rp*bb2 - hl2)
                 + 0.3f * FEXP2(cond ? (q2 - rs*hb2 - hl2) : (lco2 - hl2));

        // ---- Newton-form matrix function: p(A) = w0 + c1(A-l0) + c2(A-l0)(A-l1) ----
        float d10 = l1 - l0, d21 = l2 - l1, d20 = l2 - l0;
        d10 = copysignf(fmaxf(fabsf(d10), 1e-6f), d10);
        d21 = copysignf(fmaxf(fabsf(d21), 1e-6f), d21);
        d20 = copysignf(fmaxf(fabsf(d20), 1e-6f), d20);
        float invP = FRCP(d10 * d21 * d20);       // |prod| >= 1e-18, normal f32
        float i10 = d21 * d20 * invP;
        float i21 = d10 * d20 * invP;
        float i20 = d10 * d21 * invP;
        float c1  = (w1 - w0) * i10;
        float w12 = (w2 - w1) * i21;
        float c2  = (w12 - c1) * i20;
        // p(x) = c2 x^2 + beta x + alpha
        float beta  = c1 - c2 * (l0 + l1);
        float alpha = w0 - c1 * l0 + c2 * l0 * l1;

        // S = A^2 (symmetric)
        float s00 = b00*b00 + b01*b01 + b02*b02;
        float s01 = b00*b01 + b01*b11 + b02*b12;
        float s02 = b00*b02 + b01*b12 + b02*b22;
        float s11 = b01*b01 + b11*b11 + b12*b12;
        float s12 = b01*b02 + b11*b12 + b12*b22;
        float s22 = b02*b02 + b12*b12 + b22*b22;

        // W = c2*S + beta*A + alpha*I  (= V diag(w) V^T)
        float W00 = c2*s00 + beta*b00 + alpha;
        float W01 = c2*s01 + beta*b01;
        float W02 = c2*s02 + beta*b02;
        float W11 = c2*s11 + beta*b11 + alpha;
        float W12 = c2*s12 + beta*b12;
        float W22 = c2*s22 + beta*b22 + alpha;

        // water: 0.2 * J^(1/3) * I  (J>0 for near-identity F)
        float J = f[0]*(f[4]*f[8] - f[5]*f[7])
                - f[1]*(f[3]*f[8] - f[5]*f[6])
                + f[2]*(f[3]*f[7] - f[4]*f[6]);
        float wd = 0.2f * FEXP2(FLOG2(J) * (1.0f/3.0f));

        // out = F * W + wd * I — direct scalar stores (wave covers contiguous 2304B)
        float* gO = gOut + (size_t)(pbase + tid) * 9;
        gO[0] = f[0]*W00 + f[1]*W01 + f[2]*W02 + wd;
        gO[1] = f[0]*W01 + f[1]*W11 + f[2]*W12;
        gO[2] = f[0]*W02 + f[1]*W12 + f[2]*W22;
        gO[3] = f[3]*W00 + f[4]*W01 + f[5]*W02;
        gO[4] = f[3]*W01 + f[4]*W11 + f[5]*W12 + wd;
        gO[5] = f[3]*W02 + f[4]*W12 + f[5]*W22;
        gO[6] = f[6]*W00 + f[7]*W01 + f[8]*W02;
        gO[7] = f[6]*W01 + f[7]*W11 + f[8]*W12;
        gO[8] = f[6]*W02 + f[7]*W12 + f[8]*W22 + wd;
    }
}

extern "C" void kernel_launch(void* const* d_in, const int* in_sizes, int n_in,
                              void* d_out, int out_size, void* d_ws, size_t ws_size,
                              hipStream_t stream) {
    const float* F      = (const float*)d_in[0];
    const float* p_Elog = (const float*)d_in[1];
    const float* p_nu   = (const float*)d_in[2];
    const float* p_ys   = (const float*)d_in[3];
    const float* p_al   = (const float*)d_in[4];
    const float* p_co   = (const float*)d_in[5];
    float* out = (float*)d_out;

    const int B = in_sizes[0] / 9;
    const int nblocks = (B + 255) / 256;
    physics_svd_kernel<<<nblocks, 256, 0, stream>>>(
        F, p_Elog, p_nu, p_ys, p_al, p_co, out, B);
}